// Round 1
// baseline (344.846 us; speedup 1.0000x reference)
//
#include <hip/hip_runtime.h>
#include <hip/hip_bf16.h>

#define BSZ 4096
#define MAXLEN 200
#define EDIM 112

typedef __attribute__((ext_vector_type(8))) short bf16x8;
typedef __attribute__((ext_vector_type(4))) float f32x4;

// f32 -> bf16 (RNE), bit-level
static __device__ __forceinline__ short f2bf(float f) {
    unsigned u = __float_as_uint(f);
    unsigned r = (u + 0x7fffu + ((u >> 16) & 1u)) >> 16;
    return (short)r;
}

static __device__ __forceinline__ bf16x8 cvt8(float4 a, float4 b) {
    bf16x8 r;
    r[0] = f2bf(a.x); r[1] = f2bf(a.y); r[2] = f2bf(a.z); r[3] = f2bf(a.w);
    r[4] = f2bf(b.x); r[5] = f2bf(b.y); r[6] = f2bf(b.z); r[7] = f2bf(b.w);
    return r;
}

// d[i] = D[i][i]
__global__ __launch_bounds__(256) void extract_d(const float* __restrict__ Dm,
                                                 float* __restrict__ dvec) {
    int i = blockIdx.x * 256 + threadIdx.x;
    if (i < BSZ) dvec[i] = Dm[(size_t)i * (BSZ + 1)];
}

// One wave per session: mean-pool of gathered rows. Writes S0 and acc init.
__global__ __launch_bounds__(256) void gather_pool(const float* __restrict__ emb,
                                                   const int* __restrict__ items,
                                                   const float* __restrict__ slen,
                                                   float* __restrict__ S,
                                                   float* __restrict__ acc) {
    int wave = threadIdx.x >> 6;
    int lane = threadIdx.x & 63;
    int b = blockIdx.x * 4 + wave;
    const int* it = items + (size_t)b * MAXLEN;
    const float2* base = (const float2*)emb;  // row r: float2 index r*56 + lane
    if (lane < 56) {
        float sx = 0.f, sy = 0.f;
        #pragma unroll 4
        for (int t = 0; t < MAXLEN; ++t) {
            int idx = it[t];                          // wave-uniform (same addr)
            float wgt = idx > 0 ? 1.f : 0.f;          // idx==0 is PAD (zeros)
            int r = idx > 0 ? idx - 1 : 0;            // branchless: safe row
            float2 v = base[(size_t)r * 56 + lane];
            sx += wgt * v.x;
            sy += wgt * v.y;
        }
        float invl = 1.0f / slen[b];
        float2 o = make_float2(sx * invl, sy * invl);
        ((float2*)S)[(size_t)b * 56 + lane] = o;
        ((float2*)acc)[(size_t)b * 56 + lane] = o;
    }
}

// Load 8 consecutive f32 (if valid) and convert to bf16x8 fragment.
static __device__ __forceinline__ bf16x8 ldcvt(const float* p, bool valid) {
    if (valid) {
        float4 a = *(const float4*)p;
        float4 b = *(const float4*)(p + 4);
        return cvt8(a, b);
    }
    bf16x8 z;
    #pragma unroll
    for (int i = 0; i < 8; ++i) z[i] = 0;
    return z;
}

// T = S @ W^T   (4096x112 = [4096x112] @ [112x112]^T), output transposed bf16:
// Tt[n][j] = T[j][n].  One wave per 16-row M-tile, all 7 N-tiles. K padded to 128.
__global__ __launch_bounds__(256) void small_gemm(const float* __restrict__ S,
                                                  const float* __restrict__ W,
                                                  unsigned short* __restrict__ Tt) {
    int wave = threadIdx.x >> 6;
    int lane = threadIdx.x & 63;
    int j0 = (blockIdx.x * 4 + wave) * 16;
    int nrow = lane & 15;
    int quad = lane >> 4;

    f32x4 acc[7];
    #pragma unroll
    for (int t = 0; t < 7; ++t) acc[t] = (f32x4){0.f, 0.f, 0.f, 0.f};

    #pragma unroll
    for (int kk = 0; kk < 128; kk += 32) {
        int k = kk + quad * 8;
        bool valid = (k < EDIM);  // k multiple of 8; 104 valid, 112/120 not
        bf16x8 aF = ldcvt(S + (size_t)(j0 + nrow) * EDIM + k, valid);
        #pragma unroll
        for (int t = 0; t < 7; ++t) {
            bf16x8 bF = ldcvt(W + (size_t)(16 * t + nrow) * EDIM + k, valid);
            acc[t] = __builtin_amdgcn_mfma_f32_16x16x32_bf16(aF, bF, acc[t], 0, 0, 0);
        }
    }
    // C/D: col n = lane&15, row j = quad*4 + reg.  Store Tt[n][j] (bf16).
    #pragma unroll
    for (int t = 0; t < 7; ++t) {
        int n = 16 * t + nrow;
        uint2 pk;
        pk.x = ((unsigned)f2bf(acc[t][0]) & 0xffffu) | ((unsigned)f2bf(acc[t][1]) << 16);
        pk.y = ((unsigned)f2bf(acc[t][2]) & 0xffffu) | ((unsigned)f2bf(acc[t][3]) << 16);
        *(uint2*)(Tt + (size_t)n * BSZ + j0 + quad * 4) = pk;
    }
}

// Y = d .* (A @ T);  then per-row L2-normalize into acc (or final output).
// Block = 512 thr = 8 waves; one 16-row M-tile per block, K=4096 split 8 ways.
__global__ __launch_bounds__(512) void big_gemm(const float* __restrict__ A,
                                                const unsigned short* __restrict__ Tt,
                                                const float* __restrict__ dvec,
                                                float* __restrict__ Y,
                                                float* __restrict__ accb,
                                                float* __restrict__ out,
                                                int last) {
    __shared__ float red[8][16][EDIM];  // 57344 B
    __shared__ float norms[16];

    int wave = threadIdx.x >> 6;
    int lane = threadIdx.x & 63;
    int m0 = blockIdx.x * 16;
    int nrow = lane & 15;
    int quad = lane >> 4;

    f32x4 acc[7];
    #pragma unroll
    for (int t = 0; t < 7; ++t) acc[t] = (f32x4){0.f, 0.f, 0.f, 0.f};

    const float* Arow = A + (size_t)(m0 + nrow) * 4096;
    int kbase = wave * 512;

    for (int ks = 0; ks < 16; ++ks) {
        int k = kbase + ks * 32 + quad * 8;
        float4 a0 = *(const float4*)(Arow + k);
        float4 a1 = *(const float4*)(Arow + k + 4);
        bf16x8 aF = cvt8(a0, a1);
        #pragma unroll
        for (int t = 0; t < 7; ++t) {
            bf16x8 bF = *(const bf16x8*)(Tt + (size_t)(16 * t + nrow) * 4096 + k);
            acc[t] = __builtin_amdgcn_mfma_f32_16x16x32_bf16(aF, bF, acc[t], 0, 0, 0);
        }
    }

    // per-wave partials -> LDS
    #pragma unroll
    for (int t = 0; t < 7; ++t)
        #pragma unroll
        for (int r = 0; r < 4; ++r)
            red[wave][quad * 4 + r][16 * t + nrow] = acc[t][r];
    __syncthreads();

    // cross-wave sum + d row-scale
    for (int e = threadIdx.x; e < 16 * EDIM; e += 512) {
        int r = e / EDIM, c = e % EDIM;
        float s = 0.f;
        #pragma unroll
        for (int w = 0; w < 8; ++w) s += red[w][r][c];
        s *= dvec[m0 + r];
        red[0][r][c] = s;  // each element owned by exactly one thread
    }
    __syncthreads();

    if (threadIdx.x < 16) {
        int r = threadIdx.x;
        float ss = 0.f;
        for (int c = 0; c < EDIM; ++c) {
            float v = red[0][r][c];
            ss += v * v;
        }
        norms[r] = fmaxf(sqrtf(ss), 1e-12f);
    }
    __syncthreads();

    for (int e = threadIdx.x; e < 16 * EDIM; e += 512) {
        int r = e / EDIM, c = e % EDIM;
        float v = red[0][r][c];
        size_t o = (size_t)(m0 + r) * EDIM + c;
        Y[o] = v;  // un-normalized result feeds the next layer
        float nv = v / norms[r];
        if (last) out[o] = (accb[o] + nv) * 0.25f;
        else accb[o] += nv;
    }
}

extern "C" void kernel_launch(void* const* d_in, const int* in_sizes, int n_in,
                              void* d_out, int out_size, void* d_ws, size_t ws_size,
                              hipStream_t stream) {
    (void)in_sizes; (void)n_in; (void)out_size; (void)ws_size;
    const float* emb   = (const float*)d_in[0];
    const float* Dm    = (const float*)d_in[1];
    const float* A     = (const float*)d_in[2];
    const float* slen  = (const float*)d_in[3];
    const float* Ws    = (const float*)d_in[4];
    const int*   items = (const int*)d_in[5];
    float* out = (float*)d_out;

    char* w = (char*)d_ws;
    float* dvec = (float*)w;                          // 16 KB
    float* Sa   = (float*)(w + 16384);                // 4096*112 f32
    float* Sb   = Sa + BSZ * EDIM;
    float* accb = Sb + BSZ * EDIM;
    unsigned short* Tt = (unsigned short*)(accb + BSZ * EDIM);  // 112*4096 bf16

    extract_d<<<16, 256, 0, stream>>>(Dm, dvec);
    gather_pool<<<BSZ / 4, 256, 0, stream>>>(emb, items, slen, Sa, accb);

    float* Scur = Sa;
    float* Snext = Sb;
    for (int l = 0; l < 3; ++l) {
        small_gemm<<<64, 256, 0, stream>>>(Scur, Ws + (size_t)l * EDIM * EDIM, Tt);
        big_gemm<<<256, 512, 0, stream>>>(A, Tt, dvec, Snext, accb, out, l == 2 ? 1 : 0);
        float* tmp = Scur; Scur = Snext; Snext = tmp;
    }
}

// Round 2
// 334.485 us; speedup vs baseline: 1.0310x; 1.0310x over previous
//
#include <hip/hip_runtime.h>
#include <hip/hip_bf16.h>

#define BSZ 4096
#define MAXLEN 200
#define EDIM 112

typedef __attribute__((ext_vector_type(8))) short bf16x8;
typedef __attribute__((ext_vector_type(4))) float f32x4;

// f32 -> bf16 (RNE), bit-level
static __device__ __forceinline__ short f2bf(float f) {
    unsigned u = __float_as_uint(f);
    unsigned r = (u + 0x7fffu + ((u >> 16) & 1u)) >> 16;
    return (short)r;
}

static __device__ __forceinline__ bf16x8 cvt8(float4 a, float4 b) {
    bf16x8 r;
    r[0] = f2bf(a.x); r[1] = f2bf(a.y); r[2] = f2bf(a.z); r[3] = f2bf(a.w);
    r[4] = f2bf(b.x); r[5] = f2bf(b.y); r[6] = f2bf(b.z); r[7] = f2bf(b.w);
    return r;
}

// d[i] = D[i][i]
__global__ __launch_bounds__(256) void extract_d(const float* __restrict__ Dm,
                                                 float* __restrict__ dvec) {
    int i = blockIdx.x * 256 + threadIdx.x;
    if (i < BSZ) dvec[i] = Dm[(size_t)i * (BSZ + 1)];
}

// One BLOCK (4 waves) per session; each wave mean-pools 50 items, LDS reduce.
__global__ __launch_bounds__(256) void gather_pool(const float* __restrict__ emb,
                                                   const int* __restrict__ items,
                                                   const float* __restrict__ slen,
                                                   float* __restrict__ S,
                                                   float* __restrict__ acc) {
    __shared__ float part[4][EDIM];
    int wave = threadIdx.x >> 6;
    int lane = threadIdx.x & 63;
    int b = blockIdx.x;
    const int* it = items + (size_t)b * MAXLEN + wave * 50;
    const float2* base = (const float2*)emb;  // row r: float2 index r*56 + lane
    if (lane < 56) {
        float sx = 0.f, sy = 0.f;
        #pragma unroll 10
        for (int t = 0; t < 50; ++t) {
            int idx = it[t];                          // wave-uniform
            float wgt = idx > 0 ? 1.f : 0.f;          // idx==0 is PAD (zeros)
            int r = idx > 0 ? idx - 1 : 0;            // branchless safe row
            float2 v = base[(size_t)r * 56 + lane];
            sx += wgt * v.x;
            sy += wgt * v.y;
        }
        part[wave][lane * 2]     = sx;   // stride-2: 2-way bank alias = free
        part[wave][lane * 2 + 1] = sy;
    }
    __syncthreads();
    int c = threadIdx.x;
    if (c < EDIM) {
        float s = part[0][c] + part[1][c] + part[2][c] + part[3][c];
        s /= slen[b];
        S[(size_t)b * EDIM + c]   = s;
        acc[(size_t)b * EDIM + c] = s;
    }
}

// Load 8 consecutive f32 (if valid) and convert to bf16x8 fragment.
static __device__ __forceinline__ bf16x8 ldcvt(const float* p, bool valid) {
    if (valid) {
        float4 a = *(const float4*)p;
        float4 b = *(const float4*)(p + 4);
        return cvt8(a, b);
    }
    bf16x8 z;
    #pragma unroll
    for (int i = 0; i < 8; ++i) z[i] = 0;
    return z;
}

// T = S @ W^T, output transposed bf16: Tt[n][j] = T[j][n].
// grid (64, 7): wave -> 16-row j-tile, blockIdx.y -> N-tile. K padded to 128.
__global__ __launch_bounds__(256) void small_gemm(const float* __restrict__ S,
                                                  const float* __restrict__ W,
                                                  unsigned short* __restrict__ Tt) {
    int wave = threadIdx.x >> 6;
    int lane = threadIdx.x & 63;
    int j0 = (blockIdx.x * 4 + wave) * 16;
    int t = blockIdx.y;
    int nrow = lane & 15;
    int quad = lane >> 4;

    f32x4 acc = (f32x4){0.f, 0.f, 0.f, 0.f};

    #pragma unroll
    for (int kk = 0; kk < 128; kk += 32) {
        int k = kk + quad * 8;
        bool valid = (k < EDIM);
        bf16x8 aF = ldcvt(S + (size_t)(j0 + nrow) * EDIM + k, valid);
        bf16x8 bF = ldcvt(W + (size_t)(16 * t + nrow) * EDIM + k, valid);
        acc = __builtin_amdgcn_mfma_f32_16x16x32_bf16(aF, bF, acc, 0, 0, 0);
    }
    // C/D: col n = lane&15, row j = quad*4 + reg.  Store Tt[n][j] (bf16).
    int n = 16 * t + nrow;
    uint2 pk;
    pk.x = ((unsigned)f2bf(acc[0]) & 0xffffu) | ((unsigned)f2bf(acc[1]) << 16);
    pk.y = ((unsigned)f2bf(acc[2]) & 0xffffu) | ((unsigned)f2bf(acc[3]) << 16);
    *(uint2*)(Tt + (size_t)n * BSZ + j0 + quad * 4) = pk;
}

// Partial Y = A @ T for one K-half.  grid 512: blockIdx>>1 = 16-row M-tile,
// blockIdx&1 = K-half.  8 waves split the 2048-wide K-half; LDS reduce;
// write raw partial to Yp[half].  d-scale/norm/acc happen in layer_epilogue.
__global__ __launch_bounds__(512, 4) void big_gemm(const float* __restrict__ A,
                                                   const unsigned short* __restrict__ Tt,
                                                   float* __restrict__ Yp) {
    __shared__ float red[8][16][113];  // +1 pad: breaks 4-way bank conflict

    int wave = threadIdx.x >> 6;
    int lane = threadIdx.x & 63;
    int m0 = (blockIdx.x >> 1) * 16;
    int half = blockIdx.x & 1;
    int nrow = lane & 15;
    int quad = lane >> 4;

    f32x4 acc[7];
    #pragma unroll
    for (int t = 0; t < 7; ++t) acc[t] = (f32x4){0.f, 0.f, 0.f, 0.f};

    const float* Arow = A + (size_t)(m0 + nrow) * 4096;
    int kbase = half * 2048 + wave * 256;

    for (int ks = 0; ks < 8; ++ks) {
        int k = kbase + ks * 32 + quad * 8;
        float4 a0 = *(const float4*)(Arow + k);
        float4 a1 = *(const float4*)(Arow + k + 4);
        bf16x8 aF = cvt8(a0, a1);
        #pragma unroll
        for (int t = 0; t < 7; ++t) {
            bf16x8 bF = *(const bf16x8*)(Tt + (size_t)(16 * t + nrow) * 4096 + k);
            acc[t] = __builtin_amdgcn_mfma_f32_16x16x32_bf16(aF, bF, acc[t], 0, 0, 0);
        }
    }

    #pragma unroll
    for (int t = 0; t < 7; ++t)
        #pragma unroll
        for (int r = 0; r < 4; ++r)
            red[wave][quad * 4 + r][16 * t + nrow] = acc[t][r];
    __syncthreads();

    float* dst = Yp + (size_t)half * BSZ * EDIM;
    for (int e = threadIdx.x; e < 16 * EDIM; e += 512) {
        int r = e / EDIM, c = e % EDIM;
        float s = 0.f;
        #pragma unroll
        for (int w = 0; w < 8; ++w) s += red[w][r][c];
        dst[(size_t)(m0 + r) * EDIM + c] = s;
    }
}

// Per-row: sum the 2 K-half partials, scale by d, L2-normalize into acc/out,
// write un-normalized Y for the next layer.  One wave per row.
__global__ __launch_bounds__(256) void layer_epilogue(const float* __restrict__ Yp,
                                                      const float* __restrict__ dvec,
                                                      float* __restrict__ Y,
                                                      float* __restrict__ accb,
                                                      float* __restrict__ out,
                                                      int last) {
    int wave = threadIdx.x >> 6;
    int lane = threadIdx.x & 63;
    int b = blockIdx.x * 4 + wave;

    float2 v = make_float2(0.f, 0.f);
    size_t o2 = (size_t)b * 56 + lane;
    if (lane < 56) {
        float2 v0 = ((const float2*)Yp)[o2];
        float2 v1 = ((const float2*)(Yp + (size_t)BSZ * EDIM))[o2];
        v.x = v0.x + v1.x;
        v.y = v0.y + v1.y;
    }
    float d = dvec[b];
    v.x *= d; v.y *= d;
    float ss = v.x * v.x + v.y * v.y;
    #pragma unroll
    for (int off = 32; off; off >>= 1) ss += __shfl_xor(ss, off, 64);
    float nrm = fmaxf(sqrtf(ss), 1e-12f);
    if (lane < 56) {
        if (!last) ((float2*)Y)[o2] = v;  // next layer consumes un-normalized
        float2 nv = make_float2(v.x / nrm, v.y / nrm);
        if (last) {
            float2 a = ((const float2*)accb)[o2];
            ((float2*)out)[o2] = make_float2((a.x + nv.x) * 0.25f, (a.y + nv.y) * 0.25f);
        } else {
            float2 a = ((const float2*)accb)[o2];
            ((float2*)accb)[o2] = make_float2(a.x + nv.x, a.y + nv.y);
        }
    }
}

extern "C" void kernel_launch(void* const* d_in, const int* in_sizes, int n_in,
                              void* d_out, int out_size, void* d_ws, size_t ws_size,
                              hipStream_t stream) {
    (void)in_sizes; (void)n_in; (void)out_size; (void)ws_size;
    const float* emb   = (const float*)d_in[0];
    const float* Dm    = (const float*)d_in[1];
    const float* A     = (const float*)d_in[2];
    const float* slen  = (const float*)d_in[3];
    const float* Ws    = (const float*)d_in[4];
    const int*   items = (const int*)d_in[5];
    float* out = (float*)d_out;

    char* w = (char*)d_ws;
    float* dvec = (float*)w;                            // 16 KB slot
    float* Sa   = (float*)(w + 16384);                  // 4096*112 f32
    float* Sb   = Sa + BSZ * EDIM;
    float* accb = Sb + BSZ * EDIM;
    float* Yp   = accb + BSZ * EDIM;                    // 2 * 4096*112 f32 partials
    unsigned short* Tt = (unsigned short*)(Yp + 2 * BSZ * EDIM);  // 112*4096 bf16

    extract_d<<<16, 256, 0, stream>>>(Dm, dvec);
    gather_pool<<<BSZ, 256, 0, stream>>>(emb, items, slen, Sa, accb);

    float* Scur = Sa;
    float* Snext = Sb;
    for (int l = 0; l < 3; ++l) {
        small_gemm<<<dim3(64, 7), 256, 0, stream>>>(Scur, Ws + (size_t)l * EDIM * EDIM, Tt);
        big_gemm<<<512, 512, 0, stream>>>(A, Tt, Yp);
        layer_epilogue<<<BSZ / 4, 256, 0, stream>>>(Yp, dvec, Snext, accb, out, l == 2 ? 1 : 0);
        float* tmp = Scur; Scur = Snext; Snext = tmp;
    }
}

// Round 3
// 329.367 us; speedup vs baseline: 1.0470x; 1.0155x over previous
//
#include <hip/hip_runtime.h>
#include <hip/hip_bf16.h>

#define BSZ 4096
#define MAXLEN 200
#define EDIM 112

typedef __attribute__((ext_vector_type(8))) short bf16x8;
typedef __attribute__((ext_vector_type(4))) float f32x4;

// f32 -> bf16 (RNE), bit-level
static __device__ __forceinline__ short f2bf(float f) {
    unsigned u = __float_as_uint(f);
    unsigned r = (u + 0x7fffu + ((u >> 16) & 1u)) >> 16;
    return (short)r;
}
static __device__ __forceinline__ float bf2f(short s) {
    return __uint_as_float(((unsigned)(unsigned short)s) << 16);
}
static __device__ __forceinline__ bf16x8 cvt8(float4 a, float4 b) {
    bf16x8 r;
    r[0] = f2bf(a.x); r[1] = f2bf(a.y); r[2] = f2bf(a.z); r[3] = f2bf(a.w);
    r[4] = f2bf(b.x); r[5] = f2bf(b.y); r[6] = f2bf(b.z); r[7] = f2bf(b.w);
    return r;
}

// d[i] = D[i][i]
__global__ __launch_bounds__(256) void extract_d(const float* __restrict__ Dm,
                                                 float* __restrict__ dvec) {
    int i = blockIdx.x * 256 + threadIdx.x;
    if (i < BSZ) dvec[i] = Dm[(size_t)i * (BSZ + 1)];
}

// Streaming f32 -> bf16, 8 elems/thread; first `zgroups` groups written as zeros
// (used to prepend the PAD zero-row to the embedding table).
__global__ __launch_bounds__(256) void f32_to_bf16(const float* __restrict__ src,
                                                   unsigned short* __restrict__ dst,
                                                   int ngroups, int zgroups) {
    int g = blockIdx.x * 256 + threadIdx.x;
    if (g >= ngroups) return;
    bf16x8 o;
    if (g < zgroups) {
        #pragma unroll
        for (int i = 0; i < 8; ++i) o[i] = 0;
    } else {
        const float* p = src + (size_t)(g - zgroups) * 8;
        float4 a = *(const float4*)p;
        float4 b = *(const float4*)(p + 4);
        o = cvt8(a, b);
    }
    *(bf16x8*)(dst + (size_t)g * 8) = o;
}

// bf16-table gather+mean-pool. One block per session; 4 waves x 4 rows/wave,
// 16 B/lane loads (lane = rowgroup*14 + chunk), Ebf row 0 is zeros (PAD).
__global__ __launch_bounds__(256) void gather_pool_bf(const unsigned short* __restrict__ Ebf,
                                                      const int* __restrict__ items,
                                                      const float* __restrict__ slen,
                                                      float* __restrict__ S,
                                                      float* __restrict__ acc) {
    __shared__ float part[16][14][8];
    int wave = threadIdx.x >> 6;
    int lane = threadIdx.x & 63;
    int b = blockIdx.x;
    int rg = lane / 14;   // 0..3 for lanes 0..55
    int c  = lane % 14;
    const int* it = items + (size_t)b * MAXLEN + wave * 50;
    float a[8];
    #pragma unroll
    for (int e = 0; e < 8; ++e) a[e] = 0.f;
    if (lane < 56) {
        #pragma unroll
        for (int t = 0; t < 13; ++t) {
            int j = t * 4 + rg;
            int idx = 0;
            if (j < 50) idx = it[j];               // idx==0 -> zero row (PAD)
            bf16x8 v = *(const bf16x8*)(Ebf + (size_t)idx * EDIM + c * 8);
            #pragma unroll
            for (int e = 0; e < 8; ++e) a[e] += bf2f(v[e]);
        }
        #pragma unroll
        for (int e = 0; e < 8; ++e) part[wave * 4 + rg][c][e] = a[e];
    }
    __syncthreads();
    int tid = threadIdx.x;
    if (tid < EDIM) {
        int cc = tid >> 3, ee = tid & 7;
        float s = 0.f;
        #pragma unroll
        for (int g = 0; g < 16; ++g) s += part[g][cc][ee];
        s /= slen[b];
        S[(size_t)b * EDIM + tid]   = s;
        acc[(size_t)b * EDIM + tid] = s;
    }
}

// Fallback f32 gather (if ws can't hold the bf16 table).
__global__ __launch_bounds__(256) void gather_pool_f32(const float* __restrict__ emb,
                                                       const int* __restrict__ items,
                                                       const float* __restrict__ slen,
                                                       float* __restrict__ S,
                                                       float* __restrict__ acc) {
    __shared__ float part[4][EDIM];
    int wave = threadIdx.x >> 6;
    int lane = threadIdx.x & 63;
    int b = blockIdx.x;
    const int* it = items + (size_t)b * MAXLEN + wave * 50;
    const float2* base = (const float2*)emb;
    if (lane < 56) {
        float sx = 0.f, sy = 0.f;
        #pragma unroll 10
        for (int t = 0; t < 50; ++t) {
            int idx = it[t];
            float wgt = idx > 0 ? 1.f : 0.f;
            int r = idx > 0 ? idx - 1 : 0;
            float2 v = base[(size_t)r * 56 + lane];
            sx += wgt * v.x;
            sy += wgt * v.y;
        }
        part[wave][lane * 2]     = sx;
        part[wave][lane * 2 + 1] = sy;
    }
    __syncthreads();
    int c = threadIdx.x;
    if (c < EDIM) {
        float s = part[0][c] + part[1][c] + part[2][c] + part[3][c];
        s /= slen[b];
        S[(size_t)b * EDIM + c]   = s;
        acc[(size_t)b * EDIM + c] = s;
    }
}

// Load 8 consecutive f32 (if valid) -> bf16x8 fragment.
static __device__ __forceinline__ bf16x8 ldcvt(const float* p, bool valid) {
    if (valid) {
        float4 a = *(const float4*)p;
        float4 b = *(const float4*)(p + 4);
        return cvt8(a, b);
    }
    bf16x8 z;
    #pragma unroll
    for (int i = 0; i < 8; ++i) z[i] = 0;
    return z;
}

// T = S @ W^T, output transposed bf16: Tt[n][j] = T[j][n].
// grid (64, 7): wave -> 16-row j-tile, blockIdx.y -> N-tile. K padded to 128.
__global__ __launch_bounds__(256) void small_gemm(const float* __restrict__ S,
                                                  const float* __restrict__ W,
                                                  unsigned short* __restrict__ Tt) {
    int wave = threadIdx.x >> 6;
    int lane = threadIdx.x & 63;
    int j0 = (blockIdx.x * 4 + wave) * 16;
    int t = blockIdx.y;
    int nrow = lane & 15;
    int quad = lane >> 4;

    f32x4 acc = (f32x4){0.f, 0.f, 0.f, 0.f};

    #pragma unroll
    for (int kk = 0; kk < 128; kk += 32) {
        int k = kk + quad * 8;
        bool valid = (k < EDIM);
        bf16x8 aF = ldcvt(S + (size_t)(j0 + nrow) * EDIM + k, valid);
        bf16x8 bF = ldcvt(W + (size_t)(16 * t + nrow) * EDIM + k, valid);
        acc = __builtin_amdgcn_mfma_f32_16x16x32_bf16(aF, bF, acc, 0, 0, 0);
    }
    int n = 16 * t + nrow;
    uint2 pk;
    pk.x = ((unsigned)f2bf(acc[0]) & 0xffffu) | ((unsigned)f2bf(acc[1]) << 16);
    pk.y = ((unsigned)f2bf(acc[2]) & 0xffffu) | ((unsigned)f2bf(acc[3]) << 16);
    *(uint2*)(Tt + (size_t)n * BSZ + j0 + quad * 4) = pk;
}

// Partial Y = A @ T.  grid 1024, kc-major: mtile = blockIdx&255 (16 rows),
// kc = blockIdx>>8 (1024-wide K chunk).  kc-major keeps mtile->XCD mapping
// identical for all kc and all layers -> each XCD's 4 MB L2 holds its 512-row
// bf16 A-slice across layers.  4 waves split the chunk; LDS reduce; raw
// partial to Yp[kc].  d-scale/norm/acc in layer_epilogue.
template <bool ABF>
__global__ __launch_bounds__(256) void big_gemm(const float* __restrict__ Af,
                                                const unsigned short* __restrict__ Ab,
                                                const unsigned short* __restrict__ Tt,
                                                float* __restrict__ Yp) {
    __shared__ float red[4][16][113];  // +1 pad

    int wave = threadIdx.x >> 6;
    int lane = threadIdx.x & 63;
    int mtile = blockIdx.x & 255;
    int kc = blockIdx.x >> 8;
    int m0 = mtile * 16;
    int nrow = lane & 15;
    int quad = lane >> 4;

    f32x4 acc[7];
    #pragma unroll
    for (int t = 0; t < 7; ++t) acc[t] = (f32x4){0.f, 0.f, 0.f, 0.f};

    int kbase = kc * 1024 + wave * 256;

    for (int ks = 0; ks < 8; ++ks) {
        int k = kbase + ks * 32 + quad * 8;
        bf16x8 aF;
        if (ABF) {
            aF = *(const bf16x8*)(Ab + (size_t)(m0 + nrow) * 4096 + k);
        } else {
            const float* p = Af + (size_t)(m0 + nrow) * 4096 + k;
            float4 a0 = *(const float4*)p;
            float4 a1 = *(const float4*)(p + 4);
            aF = cvt8(a0, a1);
        }
        #pragma unroll
        for (int t = 0; t < 7; ++t) {
            bf16x8 bF = *(const bf16x8*)(Tt + (size_t)(16 * t + nrow) * 4096 + k);
            acc[t] = __builtin_amdgcn_mfma_f32_16x16x32_bf16(aF, bF, acc[t], 0, 0, 0);
        }
    }

    #pragma unroll
    for (int t = 0; t < 7; ++t)
        #pragma unroll
        for (int r = 0; r < 4; ++r)
            red[wave][quad * 4 + r][16 * t + nrow] = acc[t][r];
    __syncthreads();

    float* dst = Yp + (size_t)kc * BSZ * EDIM;
    for (int e = threadIdx.x; e < 16 * EDIM; e += 256) {
        int r = e / EDIM, c = e % EDIM;
        float s = red[0][r][c] + red[1][r][c] + red[2][r][c] + red[3][r][c];
        dst[(size_t)(m0 + r) * EDIM + c] = s;
    }
}

// Sum 4 K-chunk partials, d-scale, L2-normalize into acc/out; write
// un-normalized Y for the next layer.  One wave per row.
__global__ __launch_bounds__(256) void layer_epilogue(const float* __restrict__ Yp,
                                                      const float* __restrict__ dvec,
                                                      float* __restrict__ Y,
                                                      float* __restrict__ accb,
                                                      float* __restrict__ out,
                                                      int last) {
    int wave = threadIdx.x >> 6;
    int lane = threadIdx.x & 63;
    int b = blockIdx.x * 4 + wave;

    float2 v = make_float2(0.f, 0.f);
    size_t o2 = (size_t)b * 56 + lane;
    if (lane < 56) {
        #pragma unroll
        for (int p = 0; p < 4; ++p) {
            float2 t = ((const float2*)(Yp + (size_t)p * BSZ * EDIM))[o2];
            v.x += t.x;
            v.y += t.y;
        }
    }
    float d = dvec[b];
    v.x *= d; v.y *= d;
    float ss = v.x * v.x + v.y * v.y;
    #pragma unroll
    for (int off = 32; off; off >>= 1) ss += __shfl_xor(ss, off, 64);
    float nrm = fmaxf(sqrtf(ss), 1e-12f);
    if (lane < 56) {
        if (!last) ((float2*)Y)[o2] = v;  // next layer consumes un-normalized
        float2 nv = make_float2(v.x / nrm, v.y / nrm);
        float2 a = ((const float2*)accb)[o2];
        if (last) {
            ((float2*)out)[o2] = make_float2((a.x + nv.x) * 0.25f, (a.y + nv.y) * 0.25f);
        } else {
            ((float2*)accb)[o2] = make_float2(a.x + nv.x, a.y + nv.y);
        }
    }
}

extern "C" void kernel_launch(void* const* d_in, const int* in_sizes, int n_in,
                              void* d_out, int out_size, void* d_ws, size_t ws_size,
                              hipStream_t stream) {
    (void)in_sizes; (void)n_in; (void)out_size;
    const float* emb   = (const float*)d_in[0];
    const float* Dm    = (const float*)d_in[1];
    const float* A     = (const float*)d_in[2];
    const float* slen  = (const float*)d_in[3];
    const float* Ws    = (const float*)d_in[4];
    const int*   items = (const int*)d_in[5];
    float* out = (float*)d_out;

    char* w = (char*)d_ws;
    float* dvec = (float*)w;                                   // 16 KB slot
    float* Sa   = (float*)(w + 16384);                         // BSZ*EDIM f32
    float* Sb   = Sa + BSZ * EDIM;
    float* accb = Sb + BSZ * EDIM;
    float* Yp   = accb + BSZ * EDIM;                           // 4 * BSZ*EDIM f32
    unsigned short* Tt  = (unsigned short*)(Yp + 4 * BSZ * EDIM);  // 917504 B
    unsigned short* Ebf = (unsigned short*)((char*)Tt + 917504);   // 22400256 B
    unsigned short* Abf = (unsigned short*)((char*)Ebf + 22400256);// 33554432 B

    const size_t NEED_C = 16384 + 7ull * BSZ * EDIM * 4 + 917504;   // 13778944
    const size_t NEED_B = NEED_C + 22400256;
    const size_t NEED_A = NEED_B + 33554432;
    bool useE = ws_size >= NEED_B;
    bool useA = ws_size >= NEED_A;

    extract_d<<<16, 256, 0, stream>>>(Dm, dvec);

    if (useE) {
        // Ebf: 100001 rows x 112; groups of 8 -> 1400014; first 14 groups = zero row
        f32_to_bf16<<<5470, 256, 0, stream>>>(emb, Ebf, 1400014, 14);
        gather_pool_bf<<<BSZ, 256, 0, stream>>>(Ebf, items, slen, Sa, accb);
    } else {
        gather_pool_f32<<<BSZ, 256, 0, stream>>>(emb, items, slen, Sa, accb);
    }
    if (useA) {
        f32_to_bf16<<<8192, 256, 0, stream>>>(A, Abf, 2097152, 0);
    }

    float* Scur = Sa;
    float* Snext = Sb;
    for (int l = 0; l < 3; ++l) {
        small_gemm<<<dim3(64, 7), 256, 0, stream>>>(Scur, Ws + (size_t)l * EDIM * EDIM, Tt);
        if (useA) big_gemm<true><<<1024, 256, 0, stream>>>(nullptr, Abf, Tt, Yp);
        else      big_gemm<false><<<1024, 256, 0, stream>>>(A, nullptr, Tt, Yp);
        layer_epilogue<<<BSZ / 4, 256, 0, stream>>>(Yp, dvec, Snext, accb, out, l == 2 ? 1 : 0);
        float* tmp = Scur; Scur = Snext; Snext = tmp;
    }
}

// Round 4
// 292.027 us; speedup vs baseline: 1.1809x; 1.1279x over previous
//
#include <hip/hip_runtime.h>
#include <hip/hip_bf16.h>

#define BSZ 4096
#define MAXLEN 200
#define EDIM 112

typedef __attribute__((ext_vector_type(8))) short bf16x8;
typedef __attribute__((ext_vector_type(4))) float f32x4;

// f32 -> bf16 (RNE), bit-level
static __device__ __forceinline__ short f2bf(float f) {
    unsigned u = __float_as_uint(f);
    unsigned r = (u + 0x7fffu + ((u >> 16) & 1u)) >> 16;
    return (short)r;
}
static __device__ __forceinline__ float bf2f(short s) {
    return __uint_as_float(((unsigned)(unsigned short)s) << 16);
}
static __device__ __forceinline__ bf16x8 cvt8(float4 a, float4 b) {
    bf16x8 r;
    r[0] = f2bf(a.x); r[1] = f2bf(a.y); r[2] = f2bf(a.z); r[3] = f2bf(a.w);
    r[4] = f2bf(b.x); r[5] = f2bf(b.y); r[6] = f2bf(b.z); r[7] = f2bf(b.w);
    return r;
}
static __device__ __forceinline__ unsigned pack2(float a, float b) {
    return ((unsigned)f2bf(a) & 0xffffu) | ((unsigned)f2bf(b) << 16);
}

// Streaming f32 -> bf16; first `zgroups` 8-elem groups are zeros (PAD row).
__global__ __launch_bounds__(256) void f32_to_bf16(const float* __restrict__ src,
                                                   unsigned short* __restrict__ dst,
                                                   int ngroups, int zgroups) {
    int g = blockIdx.x * 256 + threadIdx.x;
    if (g >= ngroups) return;
    bf16x8 o;
    if (g < zgroups) {
        #pragma unroll
        for (int i = 0; i < 8; ++i) o[i] = 0;
    } else {
        const float* p = src + (size_t)(g - zgroups) * 8;
        float4 a = *(const float4*)p;
        float4 b = *(const float4*)(p + 4);
        o = cvt8(a, b);
    }
    *(bf16x8*)(dst + (size_t)g * 8) = o;
}

// bf16-table gather+mean-pool. One block per session; 4 waves x 4 rows/wave,
// 16 B/lane loads; Ebf row 0 is zeros (PAD).  Writes S and inits acc.
__global__ __launch_bounds__(256) void gather_pool_bf(const unsigned short* __restrict__ Ebf,
                                                      const int* __restrict__ items,
                                                      const float* __restrict__ slen,
                                                      float* __restrict__ S,
                                                      float* __restrict__ acc) {
    __shared__ float part[16][14][8];
    int wave = threadIdx.x >> 6;
    int lane = threadIdx.x & 63;
    int b = blockIdx.x;
    int rg = lane / 14;   // 0..3 for lanes 0..55
    int c  = lane % 14;
    const int* it = items + (size_t)b * MAXLEN + wave * 50;
    float a[8];
    #pragma unroll
    for (int e = 0; e < 8; ++e) a[e] = 0.f;
    if (lane < 56) {
        #pragma unroll
        for (int t = 0; t < 13; ++t) {
            int j = t * 4 + rg;
            int idx = 0;
            if (j < 50) idx = it[j];               // idx==0 -> zero row (PAD)
            bf16x8 v = *(const bf16x8*)(Ebf + (size_t)idx * EDIM + c * 8);
            #pragma unroll
            for (int e = 0; e < 8; ++e) a[e] += bf2f(v[e]);
        }
        #pragma unroll
        for (int e = 0; e < 8; ++e) part[wave * 4 + rg][c][e] = a[e];
    }
    __syncthreads();
    int tid = threadIdx.x;
    if (tid < EDIM) {
        int cc = tid >> 3, ee = tid & 7;
        float s = 0.f;
        #pragma unroll
        for (int g = 0; g < 16; ++g) s += part[g][cc][ee];
        s /= slen[b];
        S[(size_t)b * EDIM + tid]   = s;
        acc[(size_t)b * EDIM + tid] = s;
    }
}

// Load 8 consecutive f32 (if valid) -> bf16x8 fragment.
static __device__ __forceinline__ bf16x8 ldcvt(const float* p, bool valid) {
    if (valid) {
        float4 a = *(const float4*)p;
        float4 b = *(const float4*)(p + 4);
        return cvt8(a, b);
    }
    bf16x8 z;
    #pragma unroll
    for (int i = 0; i < 8; ++i) z[i] = 0;
    return z;
}

// Fused {epilogue of previous layer} + {T = Y @ W^T} writing B-operand
// fragments (Bsw) for big_gemm.  One wave per 16 sessions (grid 64 x 4 waves).
// MODE 0: Y = S (from gather; no norm/acc).  MODE 1: Y = d.*sum(Yp partials);
// acc += Y/||Y||; un-normalized Y stays in-kernel (never hits global).
// Bsw layout: [(k32*7 + t)*64 + lane] x 8 bf16 -> big_gemm loads lane*16B.
template <int MODE>
__global__ __launch_bounds__(256) void fused_mid(const float* __restrict__ Sin,
                                                 const float* __restrict__ Yp,
                                                 const float* __restrict__ Dm,
                                                 float* __restrict__ accb,
                                                 const float* __restrict__ W,
                                                 unsigned short* __restrict__ Bsw) {
    __shared__ unsigned short Ylds[4][16][136];  // 136: bank-skewed row stride
    int wave = threadIdx.x >> 6;
    int lane = threadIdx.x & 63;
    int gw = blockIdx.x * 4 + wave;   // 0..255
    int j0 = gw * 16;
    int nrow = lane & 15;
    int quad = lane >> 4;
    int ses = j0 + nrow;

    // ---- un-normalized Y row `ses`, cols quad*28 .. +27 ----
    float4 v[7];
    if (MODE == 0) {
        const float4* p = (const float4*)(Sin + (size_t)ses * EDIM + quad * 28);
        #pragma unroll
        for (int i = 0; i < 7; ++i) v[i] = p[i];
    } else {
        #pragma unroll
        for (int i = 0; i < 7; ++i) v[i] = make_float4(0.f, 0.f, 0.f, 0.f);
        #pragma unroll
        for (int pp = 0; pp < 4; ++pp) {
            const float4* p = (const float4*)(Yp + (size_t)pp * BSZ * EDIM
                                              + (size_t)ses * EDIM + quad * 28);
            #pragma unroll
            for (int i = 0; i < 7; ++i) {
                float4 t = p[i];
                v[i].x += t.x; v[i].y += t.y; v[i].z += t.z; v[i].w += t.w;
            }
        }
        float d = Dm[(size_t)ses * (BSZ + 1)];   // D diagonal
        float ss = 0.f;
        #pragma unroll
        for (int i = 0; i < 7; ++i) {
            v[i].x *= d; v[i].y *= d; v[i].z *= d; v[i].w *= d;
            ss += v[i].x * v[i].x + v[i].y * v[i].y + v[i].z * v[i].z + v[i].w * v[i].w;
        }
        ss += __shfl_xor(ss, 16, 64);            // reduce across the 4 quads
        ss += __shfl_xor(ss, 32, 64);
        float rinv = 1.f / fmaxf(sqrtf(ss), 1e-12f);
        float4* pa = (float4*)(accb + (size_t)ses * EDIM + quad * 28);
        #pragma unroll
        for (int i = 0; i < 7; ++i) {
            float4 a = pa[i];
            a.x += v[i].x * rinv; a.y += v[i].y * rinv;
            a.z += v[i].z * rinv; a.w += v[i].w * rinv;
            pa[i] = a;
        }
    }

    // ---- bf16 Y tile to LDS (cols 112..127 zeroed for K-padding) ----
    #pragma unroll
    for (int i = 0; i < 7; ++i) {
        uint2 pk;
        pk.x = pack2(v[i].x, v[i].y);
        pk.y = pack2(v[i].z, v[i].w);
        *(uint2*)&Ylds[wave][nrow][quad * 28 + i * 4] = pk;
    }
    *(uint2*)&Ylds[wave][nrow][112 + quad * 4] = make_uint2(0u, 0u);
    __syncthreads();

    // ---- A fragments from LDS ----
    bf16x8 aF[4];
    #pragma unroll
    for (int k32 = 0; k32 < 4; ++k32)
        aF[k32] = *(bf16x8*)&Ylds[wave][nrow][k32 * 32 + quad * 8];

    // ---- MFMA over 7 W-tiles, K = 4 x 32 (cols >=112 zero on both sides) ----
    f32x4 acc[7];
    #pragma unroll
    for (int t = 0; t < 7; ++t) acc[t] = (f32x4){0.f, 0.f, 0.f, 0.f};
    #pragma unroll
    for (int t = 0; t < 7; ++t) {
        const float* wr = W + (size_t)(16 * t + nrow) * EDIM;
        #pragma unroll
        for (int k32 = 0; k32 < 4; ++k32) {
            bf16x8 bF = ldcvt(wr + k32 * 32 + quad * 8, (k32 < 3) || (quad < 2));
            acc[t] = __builtin_amdgcn_mfma_f32_16x16x32_bf16(aF[k32], bF, acc[t], 0, 0, 0);
        }
    }

    // ---- scatter C into Bsw fragment layout ----
    // element (n=16t+nrow, j=j0+quad*4+reg) -> frag(k32=j>>5, t),
    // lane' = ((j>>3)&3)*16 + nrow, elem = j&7
    int k32f = j0 >> 5;
    int qp = ((j0 >> 4) & 1) * 2 + (quad >> 1);
    int e0 = (quad & 1) * 4;
    #pragma unroll
    for (int t = 0; t < 7; ++t) {
        uint2 pk;
        pk.x = pack2(acc[t][0], acc[t][1]);
        pk.y = pack2(acc[t][2], acc[t][3]);
        *(uint2*)(Bsw + ((size_t)(k32f * 7 + t) * 64 + qp * 16 + nrow) * 8 + e0) = pk;
    }
}

// Partial Y = A @ T.  grid 1024 kc-major (mtile = blk&255, kc = blk>>8).
// All operand loads are lane*16B contiguous (swizzled fragments).
// AMODE 0: read f32 A, cvt in-register, and WRITE Asw for later layers.
// AMODE 1: read Asw (bf16 fragments).
template <int AMODE>
__global__ __launch_bounds__(256) void big_gemm(const float* __restrict__ Af,
                                                unsigned short* __restrict__ Asw,
                                                const unsigned short* __restrict__ Bsw,
                                                float* __restrict__ Yp) {
    __shared__ float red[4][16][113];  // +1 pad

    int wave = threadIdx.x >> 6;
    int lane = threadIdx.x & 63;
    int mtile = blockIdx.x & 255;
    int kc = blockIdx.x >> 8;
    int m0 = mtile * 16;
    int nrow = lane & 15;
    int quad = lane >> 4;

    f32x4 acc[7];
    #pragma unroll
    for (int t = 0; t < 7; ++t) acc[t] = (f32x4){0.f, 0.f, 0.f, 0.f};

    for (int ks = 0; ks < 8; ++ks) {
        int k32 = kc * 32 + wave * 8 + ks;
        bf16x8 aF;
        size_t afrag = ((size_t)(mtile * 128 + k32) * 64 + lane) * 8;
        if (AMODE == 0) {
            const float* p = Af + (size_t)(m0 + nrow) * 4096 + k32 * 32 + quad * 8;
            float4 a0 = *(const float4*)p;
            float4 a1 = *(const float4*)(p + 4);
            aF = cvt8(a0, a1);
            *(bf16x8*)(Asw + afrag) = aF;    // side output for layers 2-3
        } else {
            aF = *(const bf16x8*)(Asw + afrag);
        }
        const unsigned short* bb = Bsw + ((size_t)k32 * 7 * 64 + lane) * 8;
        #pragma unroll
        for (int t = 0; t < 7; ++t) {
            bf16x8 bF = *(const bf16x8*)(bb + (size_t)t * 512);
            acc[t] = __builtin_amdgcn_mfma_f32_16x16x32_bf16(aF, bF, acc[t], 0, 0, 0);
        }
    }

    #pragma unroll
    for (int t = 0; t < 7; ++t)
        #pragma unroll
        for (int r = 0; r < 4; ++r)
            red[wave][quad * 4 + r][16 * t + nrow] = acc[t][r];
    __syncthreads();

    float* dst = Yp + (size_t)kc * BSZ * EDIM;
    for (int e = threadIdx.x; e < 16 * EDIM; e += 256) {
        int r = e / EDIM, c = e % EDIM;
        float s = red[0][r][c] + red[1][r][c] + red[2][r][c] + red[3][r][c];
        dst[(size_t)(m0 + r) * EDIM + c] = s;
    }
}

// Final: sum partials, d-scale, normalize, out = (acc + nv) / 4.
__global__ __launch_bounds__(256) void final_epilogue(const float* __restrict__ Yp,
                                                      const float* __restrict__ Dm,
                                                      const float* __restrict__ accb,
                                                      float* __restrict__ out) {
    int wave = threadIdx.x >> 6;
    int lane = threadIdx.x & 63;
    int b = blockIdx.x * 4 + wave;

    float2 v = make_float2(0.f, 0.f);
    size_t o2 = (size_t)b * 56 + lane;
    if (lane < 56) {
        #pragma unroll
        for (int p = 0; p < 4; ++p) {
            float2 t = ((const float2*)(Yp + (size_t)p * BSZ * EDIM))[o2];
            v.x += t.x;
            v.y += t.y;
        }
    }
    float d = Dm[(size_t)b * (BSZ + 1)];
    v.x *= d; v.y *= d;
    float ss = v.x * v.x + v.y * v.y;
    #pragma unroll
    for (int off = 32; off; off >>= 1) ss += __shfl_xor(ss, off, 64);
    float nrm = fmaxf(sqrtf(ss), 1e-12f);
    if (lane < 56) {
        float2 a = ((const float2*)accb)[o2];
        ((float2*)out)[o2] = make_float2((a.x + v.x / nrm) * 0.25f,
                                         (a.y + v.y / nrm) * 0.25f);
    }
}

extern "C" void kernel_launch(void* const* d_in, const int* in_sizes, int n_in,
                              void* d_out, int out_size, void* d_ws, size_t ws_size,
                              hipStream_t stream) {
    (void)in_sizes; (void)n_in; (void)out_size; (void)ws_size;
    const float* emb   = (const float*)d_in[0];
    const float* Dm    = (const float*)d_in[1];
    const float* A     = (const float*)d_in[2];
    const float* slen  = (const float*)d_in[3];
    const float* Ws    = (const float*)d_in[4];
    const int*   items = (const int*)d_in[5];
    float* out = (float*)d_out;

    // workspace layout (all 16B-aligned); total ~68 MB (ws is 256 MiB)
    char* w = (char*)d_ws;
    float* Sa   = (float*)w;                                   // 1835008 B
    float* accb = Sa + BSZ * EDIM;                             // 1835008 B
    float* Yp   = accb + BSZ * EDIM;                           // 4x1835008 B
    unsigned short* Bsw = (unsigned short*)(Yp + 4 * BSZ * EDIM);   // 917504 B
    unsigned short* Ebf = Bsw + 128 * 7 * 64 * 8;                   // 22400256 B
    unsigned short* Asw = Ebf + 100001 * EDIM;                      // 33554432 B

    // 1. embedding table -> bf16 (zero PAD row prepended)
    f32_to_bf16<<<5470, 256, 0, stream>>>(emb, Ebf, 1400014, 14);
    // 2. gather + mean-pool -> S, acc
    gather_pool_bf<<<BSZ, 256, 0, stream>>>(Ebf, items, slen, Sa, accb);
    // 3-8. three layers: fused_mid (epilogue + small GEMM) then big_gemm
    fused_mid<0><<<64, 256, 0, stream>>>(Sa, nullptr, nullptr, nullptr, Ws, Bsw);
    big_gemm<0><<<1024, 256, 0, stream>>>(A, Asw, Bsw, Yp);
    fused_mid<1><<<64, 256, 0, stream>>>(nullptr, Yp, Dm, accb,
                                         Ws + (size_t)EDIM * EDIM, Bsw);
    big_gemm<1><<<1024, 256, 0, stream>>>(nullptr, Asw, Bsw, Yp);
    fused_mid<1><<<64, 256, 0, stream>>>(nullptr, Yp, Dm, accb,
                                         Ws + (size_t)2 * EDIM * EDIM, Bsw);
    big_gemm<1><<<1024, 256, 0, stream>>>(nullptr, Asw, Bsw, Yp);
    // 9. final epilogue
    final_epilogue<<<BSZ / 4, 256, 0, stream>>>(Yp, Dm, accb, out);
}

// Round 5
// 287.896 us; speedup vs baseline: 1.1978x; 1.0143x over previous
//
#include <hip/hip_runtime.h>
#include <hip/hip_bf16.h>

#define BSZ 4096
#define MAXLEN 200
#define EDIM 112
#define NKC 16   // K-chunk partials in big_gemm

typedef __attribute__((ext_vector_type(8))) short bf16x8;
typedef __attribute__((ext_vector_type(4))) float f32x4;

// f32 -> bf16 (RNE), bit-level
static __device__ __forceinline__ short f2bf(float f) {
    unsigned u = __float_as_uint(f);
    unsigned r = (u + 0x7fffu + ((u >> 16) & 1u)) >> 16;
    return (short)r;
}
static __device__ __forceinline__ float bf2f(short s) {
    return __uint_as_float(((unsigned)(unsigned short)s) << 16);
}
static __device__ __forceinline__ bf16x8 cvt8(float4 a, float4 b) {
    bf16x8 r;
    r[0] = f2bf(a.x); r[1] = f2bf(a.y); r[2] = f2bf(a.z); r[3] = f2bf(a.w);
    r[4] = f2bf(b.x); r[5] = f2bf(b.y); r[6] = f2bf(b.z); r[7] = f2bf(b.w);
    return r;
}
static __device__ __forceinline__ unsigned pack2(float a, float b) {
    return ((unsigned)f2bf(a) & 0xffffu) | ((unsigned)f2bf(b) << 16);
}

// Streaming f32 -> bf16; first `zgroups` 8-elem groups are zeros (PAD row).
__global__ __launch_bounds__(256) void f32_to_bf16(const float* __restrict__ src,
                                                   unsigned short* __restrict__ dst,
                                                   int ngroups, int zgroups) {
    int g = blockIdx.x * 256 + threadIdx.x;
    if (g >= ngroups) return;
    bf16x8 o;
    if (g < zgroups) {
        #pragma unroll
        for (int i = 0; i < 8; ++i) o[i] = 0;
    } else {
        const float* p = src + (size_t)(g - zgroups) * 8;
        float4 a = *(const float4*)p;
        float4 b = *(const float4*)(p + 4);
        o = cvt8(a, b);
    }
    *(bf16x8*)(dst + (size_t)g * 8) = o;
}

// bf16-table gather+mean-pool. One block per session; 4 waves x 4 rows/wave,
// 16 B/lane loads; Ebf row 0 is zeros (PAD).  Writes S and inits acc.
__global__ __launch_bounds__(256) void gather_pool_bf(const unsigned short* __restrict__ Ebf,
                                                      const int* __restrict__ items,
                                                      const float* __restrict__ slen,
                                                      float* __restrict__ S,
                                                      float* __restrict__ acc) {
    __shared__ float part[16][14][8];
    int wave = threadIdx.x >> 6;
    int lane = threadIdx.x & 63;
    int b = blockIdx.x;
    int rg = lane / 14;   // 0..3 for lanes 0..55
    int c  = lane % 14;
    const int* it = items + (size_t)b * MAXLEN + wave * 50;
    float a[8];
    #pragma unroll
    for (int e = 0; e < 8; ++e) a[e] = 0.f;
    if (lane < 56) {
        #pragma unroll
        for (int t = 0; t < 13; ++t) {
            int j = t * 4 + rg;
            int idx = 0;
            if (j < 50) idx = it[j];               // idx==0 -> zero row (PAD)
            bf16x8 v = *(const bf16x8*)(Ebf + (size_t)idx * EDIM + c * 8);
            #pragma unroll
            for (int e = 0; e < 8; ++e) a[e] += bf2f(v[e]);
        }
        #pragma unroll
        for (int e = 0; e < 8; ++e) part[wave * 4 + rg][c][e] = a[e];
    }
    __syncthreads();
    int tid = threadIdx.x;
    if (tid < EDIM) {
        int cc = tid >> 3, ee = tid & 7;
        float s = 0.f;
        #pragma unroll
        for (int g = 0; g < 16; ++g) s += part[g][cc][ee];
        s /= slen[b];
        S[(size_t)b * EDIM + tid]   = s;
        acc[(size_t)b * EDIM + tid] = s;
    }
}

// Load 8 consecutive f32 (if valid) -> bf16x8 fragment.
static __device__ __forceinline__ bf16x8 ldcvt(const float* p, bool valid) {
    if (valid) {
        float4 a = *(const float4*)p;
        float4 b = *(const float4*)(p + 4);
        return cvt8(a, b);
    }
    bf16x8 z;
    #pragma unroll
    for (int i = 0; i < 8; ++i) z[i] = 0;
    return z;
}

// Fused {epilogue of previous layer} + {T = Y @ W^T} writing B-operand
// fragments (Bsw).  ONE WAVE per 16 sessions, grid 256 (spread on all CUs).
// MODE 0: Y = S (from gather).  MODE 1: Y = d.*sum(16 Yp partials);
// acc += Y/||Y||; un-normalized Y never leaves the kernel.
// Bsw layout: [(k32*7 + t)*64 + lane] x 8 bf16 -> big_gemm loads lane*16B.
template <int MODE>
__global__ __launch_bounds__(64, 4) void fused_mid(const float* __restrict__ Sin,
                                                   const float* __restrict__ Yp,
                                                   const float* __restrict__ Dm,
                                                   float* __restrict__ accb,
                                                   const float* __restrict__ W,
                                                   unsigned short* __restrict__ Bsw) {
    __shared__ unsigned short Ylds[16][136];  // 4352 B, bank-skewed rows
    int lane = threadIdx.x;
    int gw = blockIdx.x;          // 0..255
    int j0 = gw * 16;
    int nrow = lane & 15;
    int quad = lane >> 4;
    int ses = j0 + nrow;

    // ---- un-normalized Y row `ses`, cols quad*28 .. +27 ----
    float4 v[7];
    if (MODE == 0) {
        const float4* p = (const float4*)(Sin + (size_t)ses * EDIM + quad * 28);
        #pragma unroll
        for (int i = 0; i < 7; ++i) v[i] = p[i];
    } else {
        #pragma unroll
        for (int i = 0; i < 7; ++i) v[i] = make_float4(0.f, 0.f, 0.f, 0.f);
        #pragma unroll 4
        for (int pp = 0; pp < NKC; ++pp) {
            const float4* p = (const float4*)(Yp + (size_t)pp * BSZ * EDIM
                                              + (size_t)ses * EDIM + quad * 28);
            #pragma unroll
            for (int i = 0; i < 7; ++i) {
                float4 t = p[i];
                v[i].x += t.x; v[i].y += t.y; v[i].z += t.z; v[i].w += t.w;
            }
        }
        float d = Dm[(size_t)ses * (BSZ + 1)];   // D diagonal
        float ss = 0.f;
        #pragma unroll
        for (int i = 0; i < 7; ++i) {
            v[i].x *= d; v[i].y *= d; v[i].z *= d; v[i].w *= d;
            ss += v[i].x * v[i].x + v[i].y * v[i].y + v[i].z * v[i].z + v[i].w * v[i].w;
        }
        ss += __shfl_xor(ss, 16, 64);            // reduce across the 4 quads
        ss += __shfl_xor(ss, 32, 64);
        float rinv = 1.f / fmaxf(sqrtf(ss), 1e-12f);
        float4* pa = (float4*)(accb + (size_t)ses * EDIM + quad * 28);
        #pragma unroll
        for (int i = 0; i < 7; ++i) {
            float4 a = pa[i];
            a.x += v[i].x * rinv; a.y += v[i].y * rinv;
            a.z += v[i].z * rinv; a.w += v[i].w * rinv;
            pa[i] = a;
        }
    }

    // ---- bf16 Y tile to LDS (cols 112..127 zeroed for K-padding) ----
    #pragma unroll
    for (int i = 0; i < 7; ++i) {
        uint2 pk;
        pk.x = pack2(v[i].x, v[i].y);
        pk.y = pack2(v[i].z, v[i].w);
        *(uint2*)&Ylds[nrow][quad * 28 + i * 4] = pk;
    }
    *(uint2*)&Ylds[nrow][112 + quad * 4] = make_uint2(0u, 0u);
    __syncthreads();

    // ---- A fragments from LDS ----
    bf16x8 aF[4];
    #pragma unroll
    for (int k32 = 0; k32 < 4; ++k32)
        aF[k32] = *(bf16x8*)&Ylds[nrow][k32 * 32 + quad * 8];

    // ---- MFMA over 7 W-tiles, K = 4 x 32 (cols >=112 zero on both sides) ----
    f32x4 acc[7];
    #pragma unroll
    for (int t = 0; t < 7; ++t) acc[t] = (f32x4){0.f, 0.f, 0.f, 0.f};
    #pragma unroll
    for (int t = 0; t < 7; ++t) {
        const float* wr = W + (size_t)(16 * t + nrow) * EDIM;
        #pragma unroll
        for (int k32 = 0; k32 < 4; ++k32) {
            bf16x8 bF = ldcvt(wr + k32 * 32 + quad * 8, (k32 < 3) || (quad < 2));
            acc[t] = __builtin_amdgcn_mfma_f32_16x16x32_bf16(aF[k32], bF, acc[t], 0, 0, 0);
        }
    }

    // ---- scatter C into Bsw fragment layout ----
    // element (n=16t+nrow, j=j0+quad*4+reg) -> frag(k32=j>>5, t),
    // lane' = ((j>>3)&3)*16 + nrow, elem = j&7
    int k32f = j0 >> 5;
    int qp = ((j0 >> 4) & 1) * 2 + (quad >> 1);
    int e0 = (quad & 1) * 4;
    #pragma unroll
    for (int t = 0; t < 7; ++t) {
        uint2 pk;
        pk.x = pack2(acc[t][0], acc[t][1]);
        pk.y = pack2(acc[t][2], acc[t][3]);
        *(uint2*)(Bsw + ((size_t)(k32f * 7 + t) * 64 + qp * 16 + nrow) * 8 + e0) = pk;
    }
}

// Partial Y = A @ T.  SINGLE-WAVE blocks (64 thr), no LDS, no barriers.
// grid 2048: mt2 = blk&127 (32-row M-tile), kc = blk>>7 (0..15, K=256 chunk).
// Each wave: 2 A-fragments x 7 B-fragments = 14 MFMA per 9 coalesced loads.
// C scatters straight to the wave's private Yp partial (contiguous 14 KB
// region per block -> TCC write-combines).
// AMODE 0: read f32 A, cvt in-register, side-write Asw for later layers.
// AMODE 1: read Asw (bf16 fragments, lane*16B fully coalesced).
template <int AMODE>
__global__ __launch_bounds__(64, 4) void big_gemm(const float* __restrict__ Af,
                                                  unsigned short* __restrict__ Asw,
                                                  const unsigned short* __restrict__ Bsw,
                                                  float* __restrict__ Yp) {
    int lane = threadIdx.x;
    int mt2 = blockIdx.x & 127;
    int kc = blockIdx.x >> 7;
    int nrow = lane & 15;
    int quad = lane >> 4;

    f32x4 acc[2][7];
    #pragma unroll
    for (int s = 0; s < 2; ++s)
        #pragma unroll
        for (int t = 0; t < 7; ++t) acc[s][t] = (f32x4){0.f, 0.f, 0.f, 0.f};

    for (int ks = 0; ks < 8; ++ks) {
        int k32 = kc * 8 + ks;
        bf16x8 aF[2];
        #pragma unroll
        for (int sub = 0; sub < 2; ++sub) {
            int mtile = mt2 * 2 + sub;
            size_t afrag = ((size_t)(mtile * 128 + k32) * 64 + lane) * 8;
            if (AMODE == 0) {
                const float* p = Af + (size_t)(mtile * 16 + nrow) * 4096 + k32 * 32 + quad * 8;
                float4 a0 = *(const float4*)p;
                float4 a1 = *(const float4*)(p + 4);
                aF[sub] = cvt8(a0, a1);
                *(bf16x8*)(Asw + afrag) = aF[sub];   // side output for layers 2-3
            } else {
                aF[sub] = *(const bf16x8*)(Asw + afrag);
            }
        }
        const unsigned short* bb = Bsw + ((size_t)k32 * 7 * 64 + lane) * 8;
        #pragma unroll
        for (int t = 0; t < 7; ++t) {
            bf16x8 bF = *(const bf16x8*)(bb + (size_t)t * 512);
            acc[0][t] = __builtin_amdgcn_mfma_f32_16x16x32_bf16(aF[0], bF, acc[0][t], 0, 0, 0);
            acc[1][t] = __builtin_amdgcn_mfma_f32_16x16x32_bf16(aF[1], bF, acc[1][t], 0, 0, 0);
        }
    }

    // C/D: (m = sub*16 + quad*4 + r, n = 16t + nrow); 4x64B segments per store
    float* dst = Yp + (size_t)kc * BSZ * EDIM + (size_t)mt2 * 32 * EDIM;
    #pragma unroll
    for (int sub = 0; sub < 2; ++sub)
        #pragma unroll
        for (int t = 0; t < 7; ++t)
            #pragma unroll
            for (int r = 0; r < 4; ++r)
                dst[(size_t)(sub * 16 + quad * 4 + r) * EDIM + 16 * t + nrow] = acc[sub][t][r];
}

// Final: sum NKC partials, d-scale, normalize, out = (acc + nv) / 4.
__global__ __launch_bounds__(256) void final_epilogue(const float* __restrict__ Yp,
                                                      const float* __restrict__ Dm,
                                                      const float* __restrict__ accb,
                                                      float* __restrict__ out) {
    int wave = threadIdx.x >> 6;
    int lane = threadIdx.x & 63;
    int b = blockIdx.x * 4 + wave;

    float2 v = make_float2(0.f, 0.f);
    size_t o2 = (size_t)b * 56 + lane;
    if (lane < 56) {
        #pragma unroll 4
        for (int p = 0; p < NKC; ++p) {
            float2 t = ((const float2*)(Yp + (size_t)p * BSZ * EDIM))[o2];
            v.x += t.x;
            v.y += t.y;
        }
    }
    float d = Dm[(size_t)b * (BSZ + 1)];
    v.x *= d; v.y *= d;
    float ss = v.x * v.x + v.y * v.y;
    #pragma unroll
    for (int off = 32; off; off >>= 1) ss += __shfl_xor(ss, off, 64);
    float nrm = fmaxf(sqrtf(ss), 1e-12f);
    if (lane < 56) {
        float2 a = ((const float2*)accb)[o2];
        ((float2*)out)[o2] = make_float2((a.x + v.x / nrm) * 0.25f,
                                         (a.y + v.y / nrm) * 0.25f);
    }
}

extern "C" void kernel_launch(void* const* d_in, const int* in_sizes, int n_in,
                              void* d_out, int out_size, void* d_ws, size_t ws_size,
                              hipStream_t stream) {
    (void)in_sizes; (void)n_in; (void)out_size; (void)ws_size;
    const float* emb   = (const float*)d_in[0];
    const float* Dm    = (const float*)d_in[1];
    const float* A     = (const float*)d_in[2];
    const float* slen  = (const float*)d_in[3];
    const float* Ws    = (const float*)d_in[4];
    const int*   items = (const int*)d_in[5];
    float* out = (float*)d_out;

    // workspace layout (16B-aligned), ~92 MB total
    char* w = (char*)d_ws;
    float* Sa   = (float*)w;                                   // 1835008 B
    float* accb = Sa + BSZ * EDIM;                             // 1835008 B
    float* Yp   = accb + BSZ * EDIM;                           // NKC x 1835008 B
    unsigned short* Bsw = (unsigned short*)(Yp + (size_t)NKC * BSZ * EDIM); // 917504 B
    unsigned short* Ebf = Bsw + 128 * 7 * 64 * 8;                   // 22400256 B
    unsigned short* Asw = Ebf + 100001 * EDIM;                      // 33554432 B

    // 1. embedding table -> bf16 (zero PAD row prepended)
    f32_to_bf16<<<5470, 256, 0, stream>>>(emb, Ebf, 1400014, 14);
    // 2. gather + mean-pool -> S, acc
    gather_pool_bf<<<BSZ, 256, 0, stream>>>(Ebf, items, slen, Sa, accb);
    // 3-8. three layers
    fused_mid<0><<<256, 64, 0, stream>>>(Sa, nullptr, nullptr, nullptr, Ws, Bsw);
    big_gemm<0><<<2048, 64, 0, stream>>>(A, Asw, Bsw, Yp);
    fused_mid<1><<<256, 64, 0, stream>>>(nullptr, Yp, Dm, accb,
                                         Ws + (size_t)EDIM * EDIM, Bsw);
    big_gemm<1><<<2048, 64, 0, stream>>>(nullptr, Asw, Bsw, Yp);
    fused_mid<1><<<256, 64, 0, stream>>>(nullptr, Yp, Dm, accb,
                                         Ws + (size_t)2 * EDIM * EDIM, Bsw);
    big_gemm<1><<<2048, 64, 0, stream>>>(nullptr, Asw, Bsw, Yp);
    // 9. final epilogue
    final_epilogue<<<BSZ / 4, 256, 0, stream>>>(Yp, Dm, accb, out);
}